// Round 1
// baseline (786.311 us; speedup 1.0000x reference)
//
#include <hip/hip_runtime.h>

// Talking-heads attention, fully fused two-phase flash-style implementation.
// b=16, n=1024, dim=768, h=12, d=64.  All staged tensors fp16, MFMA 16x16x32 f16.
//
// Pipeline:
//  1. k_cast_x     : x (f32) -> xb (f16)
//  2. k_prep_w     : Wt = [Wq*SCALE | Wkv]^T (f16, N-major), WoT = Wo^T (f16)
//  3. k_gemm_qkv   : [q|k|v] = xb @ Wt, scattered to per-head [b][h][n][64] f16
//  4. k_transpose_v: vt[b][h][d][n] (so PV B-fragments are contiguous)
//  5. k_attn       : per (b, 16-row i-tile): phase1 stats (m,l) of softmax over
//                    mix_pre-mixed logits; phase2 recompute S, normalize, mix_post,
//                    accumulate O = Pmix @ V.  -> obuf [b][n][768] f16
//  6. k_gemm_out   : out = obuf @ WoT + bo (f32)
//
// Workspace layout (bytes), total 105,381,888:
//   xb   @ 0          (25,165,824)   -- reused as vt after gemm_qkv
//   Wt   @ 25165824   ( 3,538,944)
//   WoT  @ 28704768   ( 1,179,648)
//   qb   @ 29884416   (25,165,824)
//   kb   @ 55050240   (25,165,824)
//   vb   @ 80216064   (25,165,824)   -- reused as obuf after transpose

typedef _Float16 f16;
typedef _Float16 f16x8 __attribute__((ext_vector_type(8)));
typedef _Float16 f16x4 __attribute__((ext_vector_type(4)));
typedef float f32x4 __attribute__((ext_vector_type(4)));
typedef float fv4 __attribute__((ext_vector_type(4)));

#define MFMA(a, b, c) __builtin_amdgcn_mfma_f32_16x16x32_f16(a, b, c, 0, 0, 0)

// ---------------------------------------------------------------- cast x -> f16
__global__ __launch_bounds__(256) void k_cast_x(const float* __restrict__ x,
                                                f16* __restrict__ xb) {
  int idx = (blockIdx.x * 256 + threadIdx.x) * 8;
  fv4 a = *(const fv4*)(x + idx);
  fv4 b = *(const fv4*)(x + idx + 4);
  f16x8 o;
  o[0] = (f16)a[0]; o[1] = (f16)a[1]; o[2] = (f16)a[2]; o[3] = (f16)a[3];
  o[4] = (f16)b[0]; o[5] = (f16)b[1]; o[6] = (f16)b[2]; o[7] = (f16)b[3];
  *(f16x8*)(xb + idx) = o;
}

// ------------------------------------------- weights: transpose + cast (+scale q)
__global__ __launch_bounds__(256) void k_prep_w(const float* __restrict__ Wq,
                                                const float* __restrict__ Wkv,
                                                const float* __restrict__ Wo,
                                                f16* __restrict__ Wt,
                                                f16* __restrict__ WoT) {
  int idx = blockIdx.x * 256 + threadIdx.x;
  if (idx < 2304 * 768) {
    int n = idx / 768, k = idx % 768;
    float v = (n < 768) ? Wq[k * 768 + n] * 0.125f   // SCALE = 64^-0.5 folded here
                        : Wkv[k * 1536 + (n - 768)];
    Wt[idx] = (f16)v;
  } else {
    int id2 = idx - 2304 * 768;
    int n = id2 / 768, k = id2 % 768;
    WoT[id2] = (f16)Wo[k * 768 + n];
  }
}

// ---------------------------------------------------------------- QKV projection
__global__ __launch_bounds__(256) void k_gemm_qkv(const f16* __restrict__ A,
                                                  const f16* __restrict__ Bt,
                                                  f16* __restrict__ qb,
                                                  f16* __restrict__ kb,
                                                  f16* __restrict__ vb) {
  __shared__ f16 As[128 * 72];  // +8 pad: conflict-free b128 frag reads
  __shared__ f16 Bs[128 * 72];
  const int tid = threadIdx.x;
  const int m0 = blockIdx.y << 7;
  const int n0 = blockIdx.x << 7;
  const int lane = tid & 63, w = tid >> 6;
  const int quad = lane >> 4, col = lane & 15;
  const int wm = (w >> 1) << 6, wn = (w & 1) << 6;
  const f32x4 z4 = {0.f, 0.f, 0.f, 0.f};
  f32x4 acc[4][4];
#pragma unroll
  for (int i = 0; i < 4; ++i)
#pragma unroll
    for (int j = 0; j < 4; ++j) acc[i][j] = z4;

  for (int k0 = 0; k0 < 768; k0 += 64) {
#pragma unroll
    for (int s = 0; s < 4; ++s) {
      int u = s * 256 + tid;
      int row = u >> 3, seg = (u & 7) << 3;
      *(f16x8*)&As[row * 72 + seg] = *(const f16x8*)(A + (m0 + row) * 768 + k0 + seg);
      *(f16x8*)&Bs[row * 72 + seg] = *(const f16x8*)(Bt + (n0 + row) * 768 + k0 + seg);
    }
    __syncthreads();
#pragma unroll
    for (int kk = 0; kk < 64; kk += 32) {
      f16x8 af[4], bf[4];
#pragma unroll
      for (int ic = 0; ic < 4; ++ic)
        af[ic] = *(f16x8*)&As[(wm + ic * 16 + col) * 72 + kk + quad * 8];
#pragma unroll
      for (int jc = 0; jc < 4; ++jc)
        bf[jc] = *(f16x8*)&Bs[(wn + jc * 16 + col) * 72 + kk + quad * 8];
#pragma unroll
      for (int ic = 0; ic < 4; ++ic)
#pragma unroll
        for (int jc = 0; jc < 4; ++jc) acc[ic][jc] = MFMA(af[ic], bf[jc], acc[ic][jc]);
    }
    __syncthreads();
  }
  // epilogue: scatter to per-head q/k/v layouts
#pragma unroll
  for (int jc = 0; jc < 4; ++jc) {
    int gn = n0 + wn + jc * 16 + col;
#pragma unroll
    for (int ic = 0; ic < 4; ++ic)
#pragma unroll
      for (int r = 0; r < 4; ++r) {
        int gm = m0 + wm + ic * 16 + (quad << 2) + r;
        int b = gm >> 10, i = gm & 1023;
        f16 v = (f16)acc[ic][jc][r];
        if (gn < 768) {
          int h = gn >> 6, dd = gn & 63;
          qb[(((b * 12 + h) << 10) + i) * 64 + dd] = v;
        } else if (gn < 1536) {
          int t = gn - 768; int h = t >> 6, dd = t & 63;
          kb[(((b * 12 + h) << 10) + i) * 64 + dd] = v;
        } else {
          int t = gn - 1536; int h = t >> 6, dd = t & 63;
          vb[(((b * 12 + h) << 10) + i) * 64 + dd] = v;
        }
      }
  }
}

// ---------------------------------------------------------------- V transpose
__global__ __launch_bounds__(256) void k_transpose_v(const f16* __restrict__ vb,
                                                     f16* __restrict__ vt) {
  __shared__ f16 t[64 * 72];
  const int bh = blockIdx.x;        // 0..191
  const int n0 = blockIdx.y << 6;   // 16 tiles of 64
  const int tid = threadIdx.x;
#pragma unroll
  for (int s = 0; s < 2; ++s) {
    int u = s * 256 + tid;
    int r = u >> 3, c = (u & 7) << 3;
    *(f16x8*)&t[r * 72 + c] = *(const f16x8*)(vb + (bh * 1024 + n0 + r) * 64 + c);
  }
  __syncthreads();
#pragma unroll
  for (int s = 0; s < 2; ++s) {
    int u = s * 256 + tid;
    int d = u >> 3, c = (u & 7) << 3;
    f16x8 o;
#pragma unroll
    for (int e = 0; e < 8; ++e) o[e] = t[(c + e) * 72 + d];
    *(f16x8*)(vt + (bh * 64 + d) * 1024 + n0 + c) = o;
  }
}

// ---------------------------------------------------------------- fused attention
// block = 256 thr (4 waves) handles (b, 16 query rows).  wave w owns heads 3w..3w+2
// for S, and output heads 3w..3w+2 for PV.  j-tile = 32.
__global__ __launch_bounds__(256, 2) void k_attn(
    const f16* __restrict__ qb, const f16* __restrict__ kb, const f16* __restrict__ vt,
    const float* __restrict__ mixp, const float* __restrict__ mixq,
    f16* __restrict__ ob) {
  __shared__ f16 Blds[512 * 40];   // [elem(i*32+j)][k-slot], stride 40 halves
  __shared__ f16 Pm[16 * 16 * 40]; // [g'][i][j], stride 40
  __shared__ float m_s[256];
  __shared__ float l_s[256];

  const int tid = threadIdx.x;
  const int bid = blockIdx.x;
  const int b = bid >> 6;
  const int i0 = (bid & 63) << 4;
  const int lane = tid & 63;
  const int w = tid >> 6;
  const int quad = lane >> 4, col = lane & 15;
  const int q4 = quad << 2;
  const int w3 = w * 3, w8 = w * 8, w4 = w << 2;

  // zero Blds: k-slots >=12 stay 0 forever -> pad lanes of mix MFMAs read 0 (no 0*NaN)
  {
    f16x8 z8;
#pragma unroll
    for (int e = 0; e < 8; ++e) z8[e] = (f16)0.f;
#pragma unroll
    for (int u = 0; u < 10; ++u) *(f16x8*)&Blds[(tid + u * 256) * 8] = z8;
  }

  // mix fragments, B-operand layout: lane holds B[k=quad*8+e][n=col], zero-padded
  f16x8 b_pre, b_post;
#pragma unroll
  for (int e = 0; e < 8; ++e) {
    int hk = quad * 8 + e;
    bool ok = (hk < 12) && (col < 12);
    b_pre[e]  = ok ? (f16)mixp[hk * 12 + col] : (f16)0.f;
    b_post[e] = ok ? (f16)mixq[hk * 12 + col] : (f16)0.f;
  }

  // Q fragments (A-operand: lane holds A[m=col][k=quad*8+e]); SCALE folded into Wq
  f16x8 qf[3][2];
#pragma unroll
  for (int h3 = 0; h3 < 3; ++h3)
#pragma unroll
    for (int kc = 0; kc < 2; ++kc)
      qf[h3][kc] = *(const f16x8*)(qb + (((b * 12 + w3 + h3) << 10) + i0 + col) * 64 +
                                   kc * 32 + quad * 8);
  __syncthreads();

  // computeS: S tiles for this wave's 3 heads -> Blds[elem][h] -> barrier ->
  // mixed logits d1[u] in transposed C-layout: lane holds (elem = c0+quad*4+r, g = col)
  auto computeS = [&](int j0, f32x4 (&d1)[8]) {
    const f32x4 z4 = {0.f, 0.f, 0.f, 0.f};
    f32x4 s[3][2];
#pragma unroll
    for (int h3 = 0; h3 < 3; ++h3) {
      s[h3][0] = z4; s[h3][1] = z4;
      const f16* kbase = kb + (((b * 12 + w3 + h3) << 10) + j0) * 64;
#pragma unroll
      for (int js = 0; js < 2; ++js)
#pragma unroll
        for (int kc = 0; kc < 2; ++kc) {
          f16x8 kf = *(const f16x8*)(kbase + (js * 16 + col) * 64 + kc * 32 + quad * 8);
          s[h3][js] = MFMA(qf[h3][kc], kf, s[h3][js]);
        }
    }
#pragma unroll
    for (int h3 = 0; h3 < 3; ++h3)
#pragma unroll
      for (int js = 0; js < 2; ++js)
#pragma unroll
        for (int r = 0; r < 4; ++r)
          Blds[(((q4 + r) << 5) + js * 16 + col) * 40 + w3 + h3] = (f16)s[h3][js][r];
    __syncthreads();
#pragma unroll
    for (int u = 0; u < 8; ++u) {
      f16x8 sf = *(f16x8*)&Blds[((w8 + u) * 16 + col) * 40 + quad * 8];
      d1[u] = MFMA(sf, b_pre, z4);
    }
  };

  // ---------------- phase 1: softmax stats.  lane tracks (g=col, i=4w+ii) rows.
  float m_run[4], l_run[4];
#pragma unroll
  for (int ii = 0; ii < 4; ++ii) { m_run[ii] = -1e30f; l_run[ii] = 0.f; }

  for (int j0 = 0; j0 < 1024; j0 += 32) {
    f32x4 d1[8];
    computeS(j0, d1);
#pragma unroll
    for (int ii = 0; ii < 4; ++ii) {
      float mx = -1e30f;
#pragma unroll
      for (int uu = 0; uu < 2; ++uu)
#pragma unroll
        for (int r = 0; r < 4; ++r) mx = fmaxf(mx, d1[ii * 2 + uu][r]);
      mx = fmaxf(mx, __shfl_xor(mx, 16));
      mx = fmaxf(mx, __shfl_xor(mx, 32));
      float mnew = fmaxf(m_run[ii], mx);
      float se = 0.f;
#pragma unroll
      for (int uu = 0; uu < 2; ++uu)
#pragma unroll
        for (int r = 0; r < 4; ++r) se += __expf(d1[ii * 2 + uu][r] - mnew);
      se += __shfl_xor(se, 16);
      se += __shfl_xor(se, 32);
      l_run[ii] = l_run[ii] * __expf(m_run[ii] - mnew) + se;
      m_run[ii] = mnew;
    }
    __syncthreads();  // protect Blds before next tile's S writes
  }
  if (quad == 0) {
#pragma unroll
    for (int ii = 0; ii < 4; ++ii) {
      m_s[col * 16 + w4 + ii] = m_run[ii];
      l_s[col * 16 + w4 + ii] = l_run[ii];
    }
  }
  __syncthreads();

  float mv[4], il[4];
#pragma unroll
  for (int ii = 0; ii < 4; ++ii) {
    mv[ii] = m_s[col * 16 + w4 + ii];
    il[ii] = 1.f / l_s[col * 16 + w4 + ii];
  }

  // ---------------- phase 2: P = softmax, mix_post, O += Pmix @ V
  f32x4 oa[3][4];
  {
    const f32x4 z4 = {0.f, 0.f, 0.f, 0.f};
#pragma unroll
    for (int g = 0; g < 3; ++g)
#pragma unroll
      for (int dc = 0; dc < 4; ++dc) oa[g][dc] = z4;
  }

  for (int j0 = 0; j0 < 1024; j0 += 32) {
    f32x4 d1[8];
    computeS(j0, d1);
    // P (normalized) -> Blds[elem][g] (own elems only; no barrier needed)
#pragma unroll
    for (int u = 0; u < 8; ++u) {
      int c0 = (w8 + u) * 16;
      int ii = u >> 1;
#pragma unroll
      for (int r = 0; r < 4; ++r) {
        float P = __expf(d1[u][r] - mv[ii]) * il[ii];
        Blds[(c0 + q4 + r) * 40 + col] = (f16)P;
      }
    }
    // mix_post:  D2[c][g'] = sum_g P[c][g] * mix_post[g][g']
    f32x4 d2[8];
    {
      const f32x4 z4 = {0.f, 0.f, 0.f, 0.f};
#pragma unroll
      for (int u = 0; u < 8; ++u) {
        f16x8 pf = *(f16x8*)&Blds[((w8 + u) * 16 + col) * 40 + quad * 8];
        d2[u] = MFMA(pf, b_post, z4);
      }
    }
    // Pmix -> Pm[g'][i][j]  (4 consecutive j pack into one b64 write)
#pragma unroll
    for (int u = 0; u < 8; ++u) {
      int iloc = (w8 + u) >> 1;
      int jbase = ((u & 1) << 4) + q4;
      f16x4 pk;
#pragma unroll
      for (int r = 0; r < 4; ++r) pk[r] = (f16)d2[u][r];
      *(f16x4*)&Pm[(col * 16 + iloc) * 40 + jbase] = pk;
    }
    __syncthreads();  // Pm complete
    // PV: wave w accumulates output heads 3w..3w+2
#pragma unroll
    for (int gg = 0; gg < 3; ++gg) {
      int gp = w3 + gg;
      f16x8 af = *(f16x8*)&Pm[(gp * 16 + col) * 40 + quad * 8];
#pragma unroll
      for (int dc = 0; dc < 4; ++dc) {
        f16x8 vf = *(const f16x8*)(vt + (((b * 12 + gp) * 64 + dc * 16 + col) << 10) +
                                   j0 + quad * 8);
        oa[gg][dc] = MFMA(af, vf, oa[gg][dc]);
      }
    }
    __syncthreads();  // protect Blds/Pm for next tile
  }

  // epilogue: O (C-layout: row=quad*4+r = i, col = d) -> obuf [b][n][768]
#pragma unroll
  for (int gg = 0; gg < 3; ++gg) {
    int gp = w3 + gg;
#pragma unroll
    for (int dc = 0; dc < 4; ++dc)
#pragma unroll
      for (int r = 0; r < 4; ++r)
        ob[((b << 10) + i0 + q4 + r) * 768 + gp * 64 + dc * 16 + col] =
            (f16)oa[gg][dc][r];
  }
}

// ---------------------------------------------------------------- output GEMM
__global__ __launch_bounds__(256) void k_gemm_out(const f16* __restrict__ A,
                                                  const f16* __restrict__ Bt,
                                                  const float* __restrict__ bias,
                                                  float* __restrict__ out) {
  __shared__ f16 As[128 * 72];
  __shared__ f16 Bs[128 * 72];
  const int tid = threadIdx.x;
  const int m0 = blockIdx.y << 7;
  const int n0 = blockIdx.x << 7;
  const int lane = tid & 63, w = tid >> 6;
  const int quad = lane >> 4, col = lane & 15;
  const int wm = (w >> 1) << 6, wn = (w & 1) << 6;
  const f32x4 z4 = {0.f, 0.f, 0.f, 0.f};
  f32x4 acc[4][4];
#pragma unroll
  for (int i = 0; i < 4; ++i)
#pragma unroll
    for (int j = 0; j < 4; ++j) acc[i][j] = z4;

  for (int k0 = 0; k0 < 768; k0 += 64) {
#pragma unroll
    for (int s = 0; s < 4; ++s) {
      int u = s * 256 + tid;
      int row = u >> 3, seg = (u & 7) << 3;
      *(f16x8*)&As[row * 72 + seg] = *(const f16x8*)(A + (m0 + row) * 768 + k0 + seg);
      *(f16x8*)&Bs[row * 72 + seg] = *(const f16x8*)(Bt + (n0 + row) * 768 + k0 + seg);
    }
    __syncthreads();
#pragma unroll
    for (int kk = 0; kk < 64; kk += 32) {
      f16x8 af[4], bf[4];
#pragma unroll
      for (int ic = 0; ic < 4; ++ic)
        af[ic] = *(f16x8*)&As[(wm + ic * 16 + col) * 72 + kk + quad * 8];
#pragma unroll
      for (int jc = 0; jc < 4; ++jc)
        bf[jc] = *(f16x8*)&Bs[(wn + jc * 16 + col) * 72 + kk + quad * 8];
#pragma unroll
      for (int ic = 0; ic < 4; ++ic)
#pragma unroll
        for (int jc = 0; jc < 4; ++jc) acc[ic][jc] = MFMA(af[ic], bf[jc], acc[ic][jc]);
    }
    __syncthreads();
  }
#pragma unroll
  for (int jc = 0; jc < 4; ++jc) {
    int gn = n0 + wn + jc * 16 + col;
    float bv = bias[gn];
#pragma unroll
    for (int ic = 0; ic < 4; ++ic)
#pragma unroll
      for (int r = 0; r < 4; ++r) {
        int gm = m0 + wm + ic * 16 + (quad << 2) + r;
        out[gm * 768 + gn] = acc[ic][jc][r] + bv;
      }
  }
}

// ---------------------------------------------------------------- launcher
extern "C" void kernel_launch(void* const* d_in, const int* in_sizes, int n_in,
                              void* d_out, int out_size, void* d_ws, size_t ws_size,
                              hipStream_t stream) {
  const float* x    = (const float*)d_in[0];
  const float* Wq   = (const float*)d_in[1];
  const float* Wkv  = (const float*)d_in[2];
  const float* mixp = (const float*)d_in[3];
  const float* mixq = (const float*)d_in[4];
  const float* Wo   = (const float*)d_in[5];
  const float* bo   = (const float*)d_in[6];
  float* out = (float*)d_out;

  char* ws = (char*)d_ws;
  f16* xb  = (f16*)(ws);
  f16* Wt  = (f16*)(ws + 25165824);
  f16* WoT = (f16*)(ws + 28704768);
  f16* qb  = (f16*)(ws + 29884416);
  f16* kb  = (f16*)(ws + 55050240);
  f16* vb  = (f16*)(ws + 80216064);
  f16* vt  = xb;   // xb dead after k_gemm_qkv
  f16* obuf = vb;  // vb dead after k_transpose_v

  k_cast_x<<<dim3(6144), dim3(256), 0, stream>>>(x, xb);
  k_prep_w<<<dim3(9216), dim3(256), 0, stream>>>(Wq, Wkv, Wo, Wt, WoT);
  k_gemm_qkv<<<dim3(18, 128), dim3(256), 0, stream>>>(xb, Wt, qb, kb, vb);
  k_transpose_v<<<dim3(192, 16), dim3(256), 0, stream>>>(vb, vt);
  k_attn<<<dim3(1024), dim3(256), 0, stream>>>(qb, kb, vt, mixp, mixq, obuf);
  k_gemm_out<<<dim3(6, 128), dim3(256), 0, stream>>>(obuf, WoT, bo, out);
}